// Round 11
// baseline (49.327 us; speedup 1.0000x reference)
//
#include <hip/hip_runtime.h>
#include <hip/hip_bf16.h>

#define HD   512
#define EPS  1e-5f
#define ASTR 520   // A-tile LDS row stride in shorts
#define OSTW 132   // epilogue staging stride in floats

typedef short bf16x8 __attribute__((ext_vector_type(8)));
typedef float f32x4  __attribute__((ext_vector_type(4)));
typedef float f32x4n __attribute__((ext_vector_type(4)));   // native vec for nt builtins

__device__ __forceinline__ float bf2f(unsigned short u) {
    union { unsigned int u32; float f; } c; c.u32 = ((unsigned int)u) << 16; return c.f;
}
__device__ __forceinline__ unsigned short f2bf(float f) {
    __hip_bfloat16 h = __float2bfloat16(f);   // RNE
    return __builtin_bit_cast(unsigned short, h);
}

// ---------------------------------------------------------------------------
// K0: fp = static @ Wf^T + bf   (blocks 0..511, one wave per (b,k) pair)
//     Wob = bf16(Wo)            (blocks 512..639)
// ---------------------------------------------------------------------------
__global__ void k0_fp_conv(const float* __restrict__ sf, const float* __restrict__ Wf,
                           const float* __restrict__ bfv, const float* __restrict__ Wo,
                           float* __restrict__ fp, unsigned short* __restrict__ Wob) {
    int t = threadIdx.x;
    int blk = blockIdx.x;
    if (blk < 512) {
        int pair = blk * 4 + (t >> 6);          // 0..2047
        int b = pair >> 9;                      // /512
        int k = pair & 511;
        int lane = t & 63;
        const float4* s4 = (const float4*)(sf + b * HD + lane * 8);
        const float4* w4 = (const float4*)(Wf + (size_t)k * HD + lane * 8);
        float4 sa = s4[0], sb = s4[1], wa = w4[0], wb = w4[1];
        float p = sa.x*wa.x + sa.y*wa.y + sa.z*wa.z + sa.w*wa.w
                + sb.x*wb.x + sb.y*wb.y + sb.z*wb.z + sb.w*wb.w;
        #pragma unroll
        for (int off = 32; off; off >>= 1) p += __shfl_xor(p, off);
        if (lane == 0) fp[b * HD + k] = p + bfv[k];
    } else {
        int base = (blk - 512) * 2048 + t * 8;  // covers 512*512 = 262144 elems
        float4 a = *(const float4*)(Wo + base);
        float4 c = *(const float4*)(Wo + base + 4);
        union { unsigned short us[8]; uint4 v4; } pk;
        pk.us[0]=f2bf(a.x); pk.us[1]=f2bf(a.y); pk.us[2]=f2bf(a.z); pk.us[3]=f2bf(a.w);
        pk.us[4]=f2bf(c.x); pk.us[5]=f2bf(c.y); pk.us[6]=f2bf(c.z); pk.us[7]=f2bf(c.w);
        *(uint4*)(Wob + base) = pk.v4;
    }
}

// ---------------------------------------------------------------------------
// K1: out1b = bf16(LN(temporal + fp[b]))  -- streaming, 32 waves/CU.
// out1b written with normal (cached) stores: K2 re-reads it from L2/L3.
// ---------------------------------------------------------------------------
__global__ __launch_bounds__(512) void k1_ln1(
        const float* __restrict__ temporal, const float* __restrict__ fp,
        const float* __restrict__ g1, const float* __restrict__ b1,
        unsigned short* __restrict__ out1b) {
    int t = threadIdx.x;
    int r = blockIdx.x * 8 + (t >> 6);
    int lane = t & 63;
    int b = r >> 11;                             // 2048 rows per batch
    int c0 = lane * 8;

    const f32x4n* rp = (const f32x4n*)(temporal + (size_t)r * HD + c0);
    f32x4n x0 = __builtin_nontemporal_load(rp);      // streaming read
    f32x4n x1 = __builtin_nontemporal_load(rp + 1);
    float4 f0  = *(const float4*)(fp + b * HD + c0);
    float4 f1  = *(const float4*)(fp + b * HD + c0 + 4);

    float v[8];
    v[0]=x0[0]+f0.x; v[1]=x0[1]+f0.y; v[2]=x0[2]+f0.z; v[3]=x0[3]+f0.w;
    v[4]=x1[0]+f1.x; v[5]=x1[1]+f1.y; v[6]=x1[2]+f1.z; v[7]=x1[3]+f1.w;
    float s = 0.f, q = 0.f;
    #pragma unroll
    for (int j = 0; j < 8; ++j) { s += v[j]; q += v[j] * v[j]; }
    #pragma unroll
    for (int off = 32; off; off >>= 1) { s += __shfl_xor(s, off); q += __shfl_xor(q, off); }
    float mean = s * (1.f / HD);
    float var  = q * (1.f / HD) - mean * mean;
    float rs   = rsqrtf(var + EPS);

    float4 g1a = *(const float4*)(g1 + c0), g1b = *(const float4*)(g1 + c0 + 4);
    float4 b1a = *(const float4*)(b1 + c0), b1b = *(const float4*)(b1 + c0 + 4);
    union { unsigned short us[8]; uint4 v4; } pk;
    pk.us[0]=f2bf((v[0]-mean)*rs*g1a.x+b1a.x); pk.us[1]=f2bf((v[1]-mean)*rs*g1a.y+b1a.y);
    pk.us[2]=f2bf((v[2]-mean)*rs*g1a.z+b1a.z); pk.us[3]=f2bf((v[3]-mean)*rs*g1a.w+b1a.w);
    pk.us[4]=f2bf((v[4]-mean)*rs*g1b.x+b1b.x); pk.us[5]=f2bf((v[5]-mean)*rs*g1b.y+b1b.y);
    pk.us[6]=f2bf((v[6]-mean)*rs*g1b.z+b1b.z); pk.us[7]=f2bf((v[7]-mean)*rs*g1b.w+b1b.w);
    *(uint4*)(out1b + (size_t)r * HD + c0) = pk.v4;
}

// ---------------------------------------------------------------------------
// K2: many-block GEMM.  Tile 32 rows x 128 cols, grid = 256x4 = 1024 blocks
// (4 blocks/CU, 16 waves/CU).  Block = 256 thr (4 waves); wave owns 32 cols
// (2x2 frags).  B direct global->VGPR depth-3; A staged once in LDS (33 KB,
// aliased by the epilogue staging buffer -> still 4 blocks/CU).
// Output: vvb = proj + bo + out1  (f32), stored coalesced; LN2 done by K3.
// ---------------------------------------------------------------------------
__global__ __launch_bounds__(256) void k2_gemm(
        const unsigned short* __restrict__ A,    // out1b bf16 [8192][512]
        const unsigned short* __restrict__ Bw,   // Wo bf16 [n][k]
        const float* __restrict__ bo,
        float* __restrict__ vvb) {
    __shared__ unsigned short smem[32 * ASTR];   // 33.3 KB: As, then reused as Ost
    unsigned short* As = smem;
    float* Ost = (float*)smem;                   // alias (32 x OSTW = 16.9 KB)

    int t = threadIdx.x;
    int mb = blockIdx.x >> 2, bn = blockIdx.x & 3;
    int m0 = mb * 32, n0 = bn * 128;
    int lane = t & 63, w = t >> 6;               // w = 0..3
    int rl = lane & 15, kl = lane >> 4;

    // ---- B prefetch, depth-3 (independent of As fill) ----
    const unsigned short* Bbase = Bw + (size_t)(n0 + w * 32 + rl) * HD + kl * 8;
    bf16x8 bq[3][2];                             // statically indexed after full unroll
    #pragma unroll
    for (int s3 = 0; s3 < 3; ++s3) {
        bq[s3][0] = *(const bf16x8*)(Bbase + s3 * 32);
        bq[s3][1] = *(const bf16x8*)(Bbase + 16 * HD + s3 * 32);
    }

    // ---- As fill: 32 rows x 1 KB from out1b (L2/L3-hot) ----
    {
        int row = t >> 3, c = (t & 7) * 64;      // shorts; 8 thr x 128 B per row
        const unsigned short* src = A + (size_t)(m0 + row) * HD + c;
        #pragma unroll
        for (int j = 0; j < 8; ++j)
            *(uint4*)(&As[row * ASTR + c + j * 8]) = *(const uint4*)(src + j * 8);
    }
    __syncthreads();                             // As ready

    // ---- K-loop: 16 steps, 4 MFMA/step, B refilled 3 ahead ----
    f32x4 acc[2][2];
    acc[0][0] = (f32x4){0,0,0,0}; acc[0][1] = (f32x4){0,0,0,0};
    acc[1][0] = (f32x4){0,0,0,0}; acc[1][1] = (f32x4){0,0,0,0};

    #pragma unroll
    for (int step = 0; step < 16; ++step) {
        int kb   = step * 32;
        int slot = step % 3;                     // compile-time after unroll
        bf16x8 a0 = *(const bf16x8*)(&As[rl * ASTR + kb + kl * 8]);
        bf16x8 a1 = *(const bf16x8*)(&As[(rl + 16) * ASTR + kb + kl * 8]);
        acc[0][0] = __builtin_amdgcn_mfma_f32_16x16x32_bf16(a0, bq[slot][0], acc[0][0], 0, 0, 0);
        acc[0][1] = __builtin_amdgcn_mfma_f32_16x16x32_bf16(a0, bq[slot][1], acc[0][1], 0, 0, 0);
        acc[1][0] = __builtin_amdgcn_mfma_f32_16x16x32_bf16(a1, bq[slot][0], acc[1][0], 0, 0, 0);
        acc[1][1] = __builtin_amdgcn_mfma_f32_16x16x32_bf16(a1, bq[slot][1], acc[1][1], 0, 0, 0);
        if (step + 3 < 16) {
            bq[slot][0] = *(const bf16x8*)(Bbase + kb + 96);
            bq[slot][1] = *(const bf16x8*)(Bbase + 16 * HD + kb + 96);
        }
    }
    __syncthreads();                             // all As reads done; smem -> Ost

    // ---- epilogue: vv = proj + bo + out1 -> Ost (LDS), then coalesced store
    // C/D layout: col = n0 + w*32 + j*16 + rl, row = i*16 + kl*4 + reg
    float bov[2] = { bo[n0 + w * 32 + rl], bo[n0 + w * 32 + 16 + rl] };
    #pragma unroll
    for (int i = 0; i < 2; ++i)
        #pragma unroll
        for (int r2 = 0; r2 < 4; ++r2) {
            int row = i * 16 + kl * 4 + r2;
            #pragma unroll
            for (int j = 0; j < 2; ++j) {
                int colL = w * 32 + j * 16 + rl;
                float o1 = bf2f(A[(size_t)(m0 + row) * HD + n0 + colL]);  // L2-hit
                Ost[row * OSTW + colL] = acc[i][j][r2] + bov[j] + o1;
            }
        }
    __syncthreads();
    {
        int row = t >> 3, c = (t & 7) * 16;      // floats; 8 thr x 64 B per row
        float* dst = vvb + (size_t)(m0 + row) * HD + n0 + c;
        #pragma unroll
        for (int j = 0; j < 4; ++j)
            *(float4*)(dst + j * 4) = *(const float4*)(&Ost[row * OSTW + c + j * 4]);
    }
}

// ---------------------------------------------------------------------------
// K3: out = LN(vvb)  -- streaming row-norm, 32 waves/CU, vvb is L2/L3-hot.
// ---------------------------------------------------------------------------
__global__ __launch_bounds__(512) void k3_rownorm(
        const float* __restrict__ vvb,
        const float* __restrict__ g2, const float* __restrict__ b2,
        float* __restrict__ out) {
    int t = threadIdx.x;
    int r = blockIdx.x * 8 + (t >> 6);
    int lane = t & 63;
    int c0 = lane * 8;

    const float4* p = (const float4*)(vvb + (size_t)r * HD + c0);
    float4 v0 = p[0], v1 = p[1];
    float v[8] = { v0.x, v0.y, v0.z, v0.w, v1.x, v1.y, v1.z, v1.w };
    float s = 0.f, q = 0.f;
    #pragma unroll
    for (int j = 0; j < 8; ++j) { s += v[j]; q += v[j] * v[j]; }
    #pragma unroll
    for (int off = 32; off; off >>= 1) { s += __shfl_xor(s, off); q += __shfl_xor(q, off); }
    float mean = s * (1.f / HD);
    float var  = q * (1.f / HD) - mean * mean;
    float rs   = rsqrtf(var + EPS);

    float4 ga = *(const float4*)(g2 + c0), gb = *(const float4*)(g2 + c0 + 4);
    float4 ba = *(const float4*)(b2 + c0), bb = *(const float4*)(b2 + c0 + 4);
    f32x4n o0 = { (v[0]-mean)*rs*ga.x+ba.x, (v[1]-mean)*rs*ga.y+ba.y,
                  (v[2]-mean)*rs*ga.z+ba.z, (v[3]-mean)*rs*ga.w+ba.w };
    f32x4n o1 = { (v[4]-mean)*rs*gb.x+bb.x, (v[5]-mean)*rs*gb.y+bb.y,
                  (v[6]-mean)*rs*gb.z+bb.z, (v[7]-mean)*rs*gb.w+bb.w };
    float* op = out + (size_t)r * HD + c0;
    __builtin_nontemporal_store(o0, (f32x4n*)op);
    __builtin_nontemporal_store(o1, (f32x4n*)(op + 4));
}

// ---------------------------------------------------------------------------
extern "C" void kernel_launch(void* const* d_in, const int* in_sizes, int n_in,
                              void* d_out, int out_size, void* d_ws, size_t ws_size,
                              hipStream_t stream) {
    const float* temporal = (const float*)d_in[0];
    const float* sf  = (const float*)d_in[1];
    // d_in[2] = Wt, d_in[3] = bt : provably unused (softmax over j-constant scores -> uniform)
    const float* Wf  = (const float*)d_in[4];
    const float* bfv = (const float*)d_in[5];
    const float* Wo  = (const float*)d_in[6];
    const float* bo  = (const float*)d_in[7];
    const float* g1  = (const float*)d_in[8];
    const float* b1  = (const float*)d_in[9];
    const float* g2  = (const float*)d_in[10];
    const float* b2  = (const float*)d_in[11];

    char* ws = (char*)d_ws;
    float*          fp    = (float*)ws;                               // 8 KB
    unsigned short* Wob   = (unsigned short*)(ws + 8192);             // 512 KB
    unsigned short* out1b = (unsigned short*)(ws + 8192 + 524288);    // 8.4 MB
    float*          vvb   = (float*)(ws + 8192 + 524288 + 8388608);   // 16.8 MB

    k0_fp_conv<<<640,  256, 0, stream>>>(sf, Wf, bfv, Wo, fp, Wob);
    k1_ln1    <<<1024, 512, 0, stream>>>(temporal, fp, g1, b1, out1b);
    k2_gemm   <<<1024, 256, 0, stream>>>(out1b, Wob, bo, vvb);
    k3_rownorm<<<1024, 512, 0, stream>>>(vvb, g2, b2, (float*)d_out);
}